// Round 8
// baseline (63.117 us; speedup 1.0000x reference)
//
#include <hip/hip_runtime.h>

typedef __attribute__((ext_vector_type(8))) short short8;
typedef __attribute__((ext_vector_type(4))) float f32x4;
typedef __attribute__((ext_vector_type(4))) int   int4v;

__device__ __forceinline__ unsigned short f2bf(float f) {
  union { float f; unsigned u; } v; v.f = f;
  unsigned r = v.u + 0x7FFFu + ((v.u >> 16) & 1u);
  return (unsigned short)(r >> 16);
}

__device__ __forceinline__ short8 pack8(f32x4 a, f32x4 b) {
  short8 p;
  p[0] = (short)f2bf(a.x); p[1] = (short)f2bf(a.y);
  p[2] = (short)f2bf(a.z); p[3] = (short)f2bf(a.w);
  p[4] = (short)f2bf(b.x); p[5] = (short)f2bf(b.y);
  p[6] = (short)f2bf(b.z); p[7] = (short)f2bf(b.w);
  return p;
}

// interleave Pe (even ch) / Po (odd ch) back to channel order
__device__ __forceinline__ short8 packEO(f32x4 e, f32x4 o) {
  short8 p;
  p[0] = (short)f2bf(e.x); p[1] = (short)f2bf(o.x);
  p[2] = (short)f2bf(e.y); p[3] = (short)f2bf(o.y);
  p[4] = (short)f2bf(e.z); p[5] = (short)f2bf(o.z);
  p[6] = (short)f2bf(e.w); p[7] = (short)f2bf(o.w);
  return p;
}

// x: (8,64,64,128) f32 ; offset: (8,64,64,18) ; modulation: (8,64,64,9)
// conv_kernel: (3,3,128,256) ; bias: (256,) ; out: (8,64,64,256) f32
constexpr int KKt = 1152;
constexpr int Ff  = 256;
constexpr size_t WT_BYTES  = (size_t)KKt * Ff * 2;           // 589,824
constexpr size_t XB_BYTES  = (size_t)8 * 64 * 64 * 128 * 2;  // 8,388,608
constexpr size_t REC_BYTES = (size_t)8 * 192 * 3 * 64 * 32;  // 9,437,184

// ===================== merged prep: x->bf16 | wt transpose | tap records ====
// grid = 2048 (x) + 1152 (wt) + 1152 (rec) = 4352 blocks x 256 threads.
// wtB fragment-major: idx = ((((ch*4+ks)*16+ft)*4+kg)*16+fr)*8+j holds
// element (f = ft*16+fr, k = ch*128+ks*32+kg*8+j).
// rec[site]: {w0,w1,w2,w3 (f32), o00,o01,o10,o11 (elem offset, ch0)}, 32 B.
// site = ((b*192 + r)*3 + dxk)*64 + w  ==  ((b*576 + 9*oh + ch)*64 + w).
__global__ __launch_bounds__(256) void prep_all(
    const float* __restrict__ x, const float* __restrict__ off,
    const float* __restrict__ mo, const float* __restrict__ kf,
    unsigned short* __restrict__ wtB, unsigned short* __restrict__ xb,
    float* __restrict__ rec) {
  const int bid = blockIdx.x;
  if (bid < 2048) {
    // ---- x f32 -> bf16 ----
    int i = (bid * 256 + threadIdx.x) * 8;
    const f32x4* p = (const f32x4*)(x + i);
    *(short8*)(xb + i) = pack8(p[0], p[1]);
  } else if (bid < 2048 + 1152) {
    // ---- weight transpose/convert ----
    int idx = (bid - 2048) * 256 + threadIdx.x;
    int j  = idx & 7;
    int fr = (idx >> 3) & 15;
    int kg = (idx >> 7) & 3;
    int ft = (idx >> 9) & 15;
    int ks = (idx >> 13) & 3;
    int ch = idx >> 15;
    int k = ch * 128 + ks * 32 + kg * 8 + j;
    int f = ft * 16 + fr;
    wtB[idx] = f2bf(kf[k * Ff + f]);
  } else {
    // ---- tap records ----
    int s  = (bid - 3200) * 256 + threadIdx.x;   // [0, 294912)
    int w  = s & 63;
    int t1 = s >> 6;                 // (b*192 + r)*3 + dxk
    int dxk = t1 % 3;
    int t2  = t1 / 3;                // b*192 + r
    int r   = t2 % 192;
    int b   = t2 / 192;
    int hp  = r & 63;
    int kp  = (r >> 6) * 3 + dxk;
    int pix = (b * 64 + hp) * 64 + w;
    float oy = off[pix * 18 + kp];
    float ox = off[pix * 18 + 9 + kp];
    float mm = mo[pix * 9 + kp];
    float py = oy + (float)(hp + kp / 3);
    float px = ox + (float)(w + kp % 3);
    float y0f = floorf(py), x0f = floorf(px);
    float y0 = fminf(fmaxf(y0f, 0.f), 65.f);
    float y1 = fminf(fmaxf(y0f + 1.f, 0.f), 65.f);
    float x0 = fminf(fmaxf(x0f, 0.f), 65.f);
    float x1 = fminf(fmaxf(x0f + 1.f, 0.f), 65.f);
    float ly = fminf(fmaxf(py, 0.f), 65.f) - y0;
    float lx = fminf(fmaxf(px, 0.f), 65.f) - x0;
    // reference's corner<->weight pairing, matched exactly:
    f32x4 wv;
    wv.x = (1.f - ly) * (1.f - lx) * mm;   // (y0,x0)
    wv.y = (1.f - ly) * lx * mm;           // (y1,x0)
    wv.z = ly * (1.f - lx) * mm;           // (y0,x1)
    wv.w = ly * lx * mm;                   // (y1,x1)
    const int iy0 = (int)y0, iy1 = (int)y1, ix0 = (int)x0, ix1 = (int)x1;
    const int yy[4] = {iy0, iy1, iy0, iy1};
    const int xx[4] = {ix0, ix0, ix1, ix1};
    int4v ov;
#pragma unroll
    for (int j2 = 0; j2 < 4; ++j2) {
      const bool v = (yy[j2] >= 1) & (yy[j2] <= 64) & (xx[j2] >= 1) & (xx[j2] <= 64);
      int o = ((b * 64 + yy[j2] - 1) * 64 + (xx[j2] - 1)) * 128;
      if (!v) { o = 0; wv[j2] = 0.f; }
      ov[j2] = o;
    }
    ((f32x4*)rec)[s * 2]     = wv;
    ((int4v*)rec)[s * 2 + 1] = ov;
  }
}

// ===================== primary: 512 blocks x 1024 threads (16 waves) ========
// Waves = 2x8 grid: mh = wv&1 (32 M-rows), fq = wv>>1 (32 F-cols). 2 blk/CU.
// Deep pipeline: gathers for chunk ch+2 issued at iter ch, combined at top of
// iter ch+1 (~full-iteration latency cover). Records replace in-loop calcW.
__global__ __launch_bounds__(1024, 8) void dcn_rec(
    const unsigned short* __restrict__ xb, const unsigned short* __restrict__ wtB,
    const float* __restrict__ rec, const float* __restrict__ bias,
    float* __restrict__ out) {
  __shared__ __align__(16) char At[2][64 * 272];   // row stride 272 B, bank-uniform

  const int b  = blockIdx.x & 7;      // one batch image per XCD (L2-resident)
  const int oh = blockIdx.x >> 3;
  const int t  = threadIdx.x;
  const int lane = t & 63;
  const int wv   = t >> 6;
  const int mh   = wv & 1;
  const int fq   = wv >> 1;
  const int fr   = lane & 15;
  const int kg   = lane >> 4;
  const int sow  = t >> 4;            // staging: 16 threads per row
  const int c8   = t & 15;            // 8-channel group

  f32x4 acc[2][2];
#pragma unroll
  for (int i = 0; i < 2; ++i) { acc[i][0] = f32x4{0,0,0,0}; acc[i][1] = f32x4{0,0,0,0}; }

  // per-thread record pointer: rec chunks for this block are contiguous
  const f32x4* rp = (const f32x4*)rec + (size_t)((b * 576 + 9 * oh) * 64) * 2;

  auto ldR = [&](int ch, f32x4& w4, int4v& o4) {
    const f32x4* p = rp + (ch * 64 + sow) * 2;
    w4 = p[0];
    o4 = *(const int4v*)(p + 1);
  };
  auto issueG = [&](int4v o4, short8* q) {
    q[0] = *(const short8*)(xb + o4.x + c8 * 8);
    q[1] = *(const short8*)(xb + o4.y + c8 * 8);
    q[2] = *(const short8*)(xb + o4.z + c8 * 8);
    q[3] = *(const short8*)(xb + o4.w + c8 * 8);
  };
  auto accQ = [&](short8 s, float w, f32x4& Pe, f32x4& Po) {
    union { short8 s; unsigned u[4]; } v; v.s = s;
#pragma unroll
    for (int i = 0; i < 4; ++i) {
      union { unsigned u; float f; } e, o;
      e.u = v.u[i] << 16;
      o.u = v.u[i] & 0xffff0000u;
      Pe[i] = fmaf(w, e.f, Pe[i]);
      Po[i] = fmaf(w, o.f, Po[i]);
    }
  };
  auto combine = [&](const short8* q, f32x4 w4) -> short8 {
    f32x4 Pe{0,0,0,0}, Po{0,0,0,0};
    accQ(q[0], w4.x, Pe, Po);
    accQ(q[1], w4.y, Pe, Po);
    accQ(q[2], w4.z, Pe, Po);
    accQ(q[3], w4.w, Pe, Po);
    return packEO(Pe, Po);
  };
  auto mmah = [&](int buf, int ch, int ks) {
    const unsigned short* bp = wtB + (((ch * 4 + ks) * 16 + fq * 2) * 64 + lane) * 8;
    short8 bf0 = *(const short8*)bp;
    short8 bf1 = *(const short8*)(bp + 512);
    short8 af[2];
#pragma unroll
    for (int m2 = 0; m2 < 2; ++m2)
      af[m2] = *(const short8*)(At[buf] + (mh * 32 + m2 * 16 + fr) * 272 + ks * 64 + kg * 16);
#pragma unroll
    for (int m2 = 0; m2 < 2; ++m2) {
      acc[m2][0] = __builtin_amdgcn_mfma_f32_16x16x32_bf16(af[m2], bf0, acc[m2][0], 0, 0, 0);
      acc[m2][1] = __builtin_amdgcn_mfma_f32_16x16x32_bf16(af[m2], bf1, acc[m2][1], 0, 0, 0);
    }
  };

  const int wb = sow * 272 + c8 * 16;

  short8 q[4];
  f32x4  w4s[2];      // w4s[k&1] holds weights of chunk k (parity-indexed, unrolled)
  int4v  o4;

  // ---- prologue: G[0] -> combine -> At[0]; issue G[1] ----
  ldR(0, w4s[0], o4);
  issueG(o4, q);
  {
    int4v o4b;
    ldR(1, w4s[1], o4b);
    *(short8*)(At[0] + wb) = combine(q, w4s[0]);
    issueG(o4b, q);                       // G[1]
  }
  __syncthreads();

  // ---- main loop: 1 barrier/chunk ----
#pragma unroll
  for (int ch = 0; ch < 9; ++ch) {
    const int buf = ch & 1;
    int4v o4n;
    if (ch < 7) ldR(ch + 2, w4s[ch & 1], o4n);          // R[ch+2] (w into slot ch&1)
    if (ch < 8)
      *(short8*)(At[buf ^ 1] + wb) = combine(q, w4s[(ch + 1) & 1]);  // stage ch+1
    mmah(buf, ch, 0);
    mmah(buf, ch, 1);
    if (ch < 7) issueG(o4n, q);                         // G[ch+2], lands next iter
    mmah(buf, ch, 2);
    mmah(buf, ch, 3);
    __syncthreads();
  }

  // ---- epilogue: D layout col(F)=lane&15, row(M)=(lane>>4)*4+reg ----
  float bs[2];
#pragma unroll
  for (int nb = 0; nb < 2; ++nb) bs[nb] = bias[fq * 32 + nb * 16 + fr];
  float* orow = out + (long)(b * 64 + oh) * 64 * 256;
#pragma unroll
  for (int m2 = 0; m2 < 2; ++m2) {
#pragma unroll
    for (int j = 0; j < 4; ++j) {
      const int row = mh * 32 + m2 * 16 + kg * 4 + j;
#pragma unroll
      for (int nb = 0; nb < 2; ++nb)
        orow[row * 256 + fq * 32 + nb * 16 + fr] = acc[m2][nb][j] + bs[nb];
    }
  }
}

// ===================== fallback (ws < WT+XB+REC): R7 kernels ================
__global__ void wt_prep(const float* __restrict__ kf, unsigned short* __restrict__ wtB) {
  int idx = blockIdx.x * 256 + threadIdx.x;
  int j  = idx & 7;
  int fr = (idx >> 3) & 15;
  int kg = (idx >> 7) & 3;
  int ft = (idx >> 9) & 15;
  int ks = (idx >> 13) & 3;
  int ch = idx >> 15;
  int k = ch * 128 + ks * 32 + kg * 8 + j;
  int f = ft * 16 + fr;
  wtB[idx] = f2bf(kf[k * Ff + f]);
}

__global__ void x_prep(const float* __restrict__ x, unsigned short* __restrict__ xb) {
  int i = (blockIdx.x * 512 + threadIdx.x) * 8;
  const f32x4* p = (const f32x4*)(x + i);
  *(short8*)(xb + i) = pack8(p[0], p[1]);
}

__global__ __launch_bounds__(1024, 8) void dcn_bf16(
    const unsigned short* __restrict__ xb, const float* __restrict__ off,
    const float* __restrict__ mo, const unsigned short* __restrict__ wtB,
    const float* __restrict__ bias, float* __restrict__ out) {
  __shared__ __align__(16) char At[2][64 * 272];
  const int b  = blockIdx.x & 7;
  const int oh = blockIdx.x >> 3;
  const int t  = threadIdx.x;
  const int lane = t & 63;
  const int wv   = t >> 6;
  const int mh   = wv & 1;
  const int fq   = wv >> 1;
  const int fr   = lane & 15;
  const int kg   = lane >> 4;
  const int sow  = t >> 4;
  const int c8   = t & 15;

  f32x4 acc[2][2];
#pragma unroll
  for (int i = 0; i < 2; ++i) { acc[i][0] = f32x4{0,0,0,0}; acc[i][1] = f32x4{0,0,0,0}; }
  float oyr[2], oxr[2], mmr[2];
  int   og[4]; float wg[4];

  auto loadOff = [&](int ch, int sl) {
    const int dy = ch / 3, dxk = ch - dy * 3;
    const int r = 3 * oh + dy, hp = r & 63, kp = ((r >> 6) * 3) + dxk;
    const int pix = (b * 64 + hp) * 64 + sow;
    oyr[sl] = off[pix * 18 + kp];
    oxr[sl] = off[pix * 18 + 9 + kp];
    mmr[sl] = mo[pix * 9 + kp];
  };
  auto calcW = [&](int ch, int sl) {
    const int dy = ch / 3, dxk = ch - dy * 3;
    const int r = 3 * oh + dy, hp = r & 63, kp = ((r >> 6) * 3) + dxk;
    const float py = oyr[sl] + (float)(hp + kp / 3);
    const float px = oxr[sl] + (float)(sow + kp % 3);
    const float mm = mmr[sl];
    const float y0f = floorf(py), x0f = floorf(px);
    const float y0 = fminf(fmaxf(y0f, 0.f), 65.f);
    const float y1 = fminf(fmaxf(y0f + 1.f, 0.f), 65.f);
    const float x0 = fminf(fmaxf(x0f, 0.f), 65.f);
    const float x1 = fminf(fmaxf(x0f + 1.f, 0.f), 65.f);
    const float ly = fminf(fmaxf(py, 0.f), 65.f) - y0;
    const float lx = fminf(fmaxf(px, 0.f), 65.f) - x0;
    wg[0] = (1.f - ly) * (1.f - lx) * mm;
    wg[1] = (1.f - ly) * lx * mm;
    wg[2] = ly * (1.f - lx) * mm;
    wg[3] = ly * lx * mm;
    const int iy0 = (int)y0, iy1 = (int)y1, ix0 = (int)x0, ix1 = (int)x1;
    const int yy[4] = {iy0, iy1, iy0, iy1};
    const int xx[4] = {ix0, ix0, ix1, ix1};
#pragma unroll
    for (int j = 0; j < 4; ++j) {
      const bool v = (yy[j] >= 1) & (yy[j] <= 64) & (xx[j] >= 1) & (xx[j] <= 64);
      int o = ((b * 64 + yy[j] - 1) * 64 + (xx[j] - 1)) * 128 + c8 * 8;
      if (!v) { o = 0; wg[j] = 0.f; }
      og[j] = o;
    }
  };
  auto ldQ = [&](int c) -> short8 { return *(const short8*)(xb + og[c]); };
  auto accQ = [&](short8 s, float w, f32x4& Pe, f32x4& Po) {
    union { short8 s; unsigned u[4]; } v; v.s = s;
#pragma unroll
    for (int i = 0; i < 4; ++i) {
      union { unsigned u; float f; } e, o;
      e.u = v.u[i] << 16;
      o.u = v.u[i] & 0xffff0000u;
      Pe[i] = fmaf(w, e.f, Pe[i]);
      Po[i] = fmaf(w, o.f, Po[i]);
    }
  };
  auto mmah = [&](int buf, int ch, int ks) {
    const unsigned short* bp = wtB + (((ch * 4 + ks) * 16 + fq * 2) * 64 + lane) * 8;
    short8 bf0 = *(const short8*)bp;
    short8 bf1 = *(const short8*)(bp + 512);
    short8 af[2];
#pragma unroll
    for (int m2 = 0; m2 < 2; ++m2)
      af[m2] = *(const short8*)(At[buf] + (mh * 32 + m2 * 16 + fr) * 272 + ks * 64 + kg * 16);
#pragma unroll
    for (int m2 = 0; m2 < 2; ++m2) {
      acc[m2][0] = __builtin_amdgcn_mfma_f32_16x16x32_bf16(af[m2], bf0, acc[m2][0], 0, 0, 0);
      acc[m2][1] = __builtin_amdgcn_mfma_f32_16x16x32_bf16(af[m2], bf1, acc[m2][1], 0, 0, 0);
    }
  };
  const int wb = sow * 272 + c8 * 16;
  loadOff(0, 0); loadOff(1, 1);
  calcW(0, 0);
  {
    short8 q0 = ldQ(0), q1 = ldQ(1), q2 = ldQ(2), q3 = ldQ(3);
    f32x4 Pe{0,0,0,0}, Po{0,0,0,0};
    accQ(q0, wg[0], Pe, Po); accQ(q1, wg[1], Pe, Po);
    accQ(q2, wg[2], Pe, Po); accQ(q3, wg[3], Pe, Po);
    *(short8*)(At[0] + wb) = packEO(Pe, Po);
  }
  __syncthreads();
#pragma unroll
  for (int ch = 0; ch < 9; ++ch) {
    const int buf = ch & 1;
    const bool hv = ch < 8;
    short8 q0, q1, q2, q3;
    f32x4 Pe{0,0,0,0}, Po{0,0,0,0};
    if (hv) {
      calcW(ch + 1, (ch + 1) & 1);
      q0 = ldQ(0); q1 = ldQ(1);
    }
    mmah(buf, ch, 0);
    if (hv) {
      q2 = ldQ(2); q3 = ldQ(3);
      accQ(q0, wg[0], Pe, Po);
    }
    mmah(buf, ch, 1);
    if (hv) accQ(q1, wg[1], Pe, Po);
    if (ch < 7) loadOff(ch + 2, ch & 1);
    mmah(buf, ch, 2);
    if (hv) {
      accQ(q2, wg[2], Pe, Po);
      accQ(q3, wg[3], Pe, Po);
      *(short8*)(At[buf ^ 1] + wb) = packEO(Pe, Po);
    }
    mmah(buf, ch, 3);
    __syncthreads();
  }
  float bs[2];
#pragma unroll
  for (int nb = 0; nb < 2; ++nb) bs[nb] = bias[fq * 32 + nb * 16 + fr];
  float* orow = out + (long)(b * 64 + oh) * 64 * 256;
#pragma unroll
  for (int m2 = 0; m2 < 2; ++m2) {
#pragma unroll
    for (int j = 0; j < 4; ++j) {
      const int row = mh * 32 + m2 * 16 + kg * 4 + j;
#pragma unroll
      for (int nb = 0; nb < 2; ++nb)
        orow[row * 256 + fq * 32 + nb * 16 + fr] = acc[m2][nb][j] + bs[nb];
    }
  }
}

extern "C" void kernel_launch(void* const* d_in, const int* in_sizes, int n_in,
                              void* d_out, int out_size, void* d_ws, size_t ws_size,
                              hipStream_t stream) {
  const float* x    = (const float*)d_in[0];
  const float* off  = (const float*)d_in[1];
  const float* mo   = (const float*)d_in[2];
  const float* kf   = (const float*)d_in[3];
  const float* bias = (const float*)d_in[4];
  float* outp = (float*)d_out;
  unsigned short* wtB = (unsigned short*)d_ws;
  unsigned short* xb  = (unsigned short*)((char*)d_ws + WT_BYTES);

  if (ws_size >= WT_BYTES + XB_BYTES + REC_BYTES) {
    float* rec = (float*)((char*)d_ws + WT_BYTES + XB_BYTES);
    prep_all<<<4352, 256, 0, stream>>>(x, off, mo, kf, wtB, xb, rec);
    dcn_rec<<<512, 1024, 0, stream>>>(xb, wtB, rec, bias, outp);
  } else {
    wt_prep<<<1152, 256, 0, stream>>>(kf, wtB);
    x_prep<<<1024, 512, 0, stream>>>(x, xb);
    dcn_bf16<<<512, 1024, 0, stream>>>(xb, off, mo, wtB, bias, outp);
  }
}

// Round 9
// 60.072 us; speedup vs baseline: 1.0507x; 1.0507x over previous
//
#include <hip/hip_runtime.h>

typedef __attribute__((ext_vector_type(8))) short short8;
typedef __attribute__((ext_vector_type(4))) float f32x4;

__device__ __forceinline__ unsigned short f2bf(float f) {
  union { float f; unsigned u; } v; v.f = f;
  unsigned r = v.u + 0x7FFFu + ((v.u >> 16) & 1u);
  return (unsigned short)(r >> 16);
}

__device__ __forceinline__ short8 pack8(f32x4 a, f32x4 b) {
  short8 p;
  p[0] = (short)f2bf(a.x); p[1] = (short)f2bf(a.y);
  p[2] = (short)f2bf(a.z); p[3] = (short)f2bf(a.w);
  p[4] = (short)f2bf(b.x); p[5] = (short)f2bf(b.y);
  p[6] = (short)f2bf(b.z); p[7] = (short)f2bf(b.w);
  return p;
}

// interleave Pe (even ch) / Po (odd ch) back to channel order
__device__ __forceinline__ short8 packEO(f32x4 e, f32x4 o) {
  short8 p;
  p[0] = (short)f2bf(e.x); p[1] = (short)f2bf(o.x);
  p[2] = (short)f2bf(e.y); p[3] = (short)f2bf(o.y);
  p[4] = (short)f2bf(e.z); p[5] = (short)f2bf(o.z);
  p[6] = (short)f2bf(e.w); p[7] = (short)f2bf(o.w);
  return p;
}

// x: (8,64,64,128) f32 ; offset: (8,64,64,18) ; modulation: (8,64,64,9)
// conv_kernel: (3,3,128,256) ; bias: (256,) ; out: (8,64,64,256) f32
// GEMM view: M=32768 (b,oh,ow), K=1152, N=256.
constexpr int KKt = 1152;
constexpr int Ff  = 256;
constexpr size_t WT_BYTES = (size_t)KKt * Ff * 2;            // 589,824
constexpr size_t XB_BYTES = (size_t)8 * 64 * 64 * 128 * 2;   // 8,388,608
constexpr size_t FE_BYTES = (size_t)32768 * KKt * 2;         // 75,497,472

#define GLOAD_LDS16(g, l)                                          \
  __builtin_amdgcn_global_load_lds(                                \
      (const __attribute__((address_space(1))) void*)(g),          \
      (__attribute__((address_space(3))) void*)(l), 16, 0, 0)

// ============ k1: x->bf16 (2048 blocks) | wt transpose (1152 blocks) =======
// wtB fragment-major: idx = ((((ch*4+ks)*16+ft)*4+kg)*16+fr)*8+j holds
// element (f = ft*16+fr, k = ch*128+ks*32+kg*8+j).
__global__ __launch_bounds__(256) void prep_small(
    const float* __restrict__ x, const float* __restrict__ kf,
    unsigned short* __restrict__ xb, unsigned short* __restrict__ wtB) {
  const int bid = blockIdx.x;
  if (bid < 2048) {
    int i = (bid * 256 + threadIdx.x) * 8;
    const f32x4* p = (const f32x4*)(x + i);
    *(short8*)(xb + i) = pack8(p[0], p[1]);
  } else {
    int idx = (bid - 2048) * 256 + threadIdx.x;
    int j  = idx & 7;
    int fr = (idx >> 3) & 15;
    int kg = (idx >> 7) & 3;
    int ft = (idx >> 9) & 15;
    int ks = (idx >> 13) & 3;
    int ch = idx >> 15;
    int k = ch * 128 + ks * 32 + kg * 8 + j;
    int f = ft * 16 + fr;
    wtB[idx] = f2bf(kf[k * Ff + f]);
  }
}

// ============ k2: feats gather/combine, barrier-free =======================
// One block per (b,oh): 1024 threads, thread = (sow=row, c8=8-ch group).
// Writes feats pre-swizzled in GEMM tile layout:
//   feats[(kstep*256 + mt)*16384 + r*128 + ((c8&7)*16 ^ ((r&7)<<4))]
// where mt = b*32 + oh/2, r = (oh&1)*64 + sow, kstep = ch*2 + (c8>=8).
__global__ __launch_bounds__(1024, 8) void feats_prep(
    const unsigned short* __restrict__ xb, const float* __restrict__ off,
    const float* __restrict__ mo, char* __restrict__ feats) {
  const int b  = blockIdx.x & 7;     // one batch image per XCD (xb L2-resident)
  const int oh = blockIdx.x >> 3;
  const int t  = threadIdx.x;
  const int sow = t >> 4;
  const int c8  = t & 15;
  const int r   = ((oh & 1) << 6) | sow;
  const int mt  = (b << 5) | (oh >> 1);
  const int swz = ((c8 & 7) << 4) ^ ((sow & 7) << 4);

  for (int ch = 0; ch < 9; ++ch) {
    const int dy = ch / 3, dxk = ch - dy * 3;
    const int rr = 3 * oh + dy, hp = rr & 63, kp = ((rr >> 6) * 3) + dxk;
    const int pix = (b * 64 + hp) * 64 + sow;
    const float oy = off[pix * 18 + kp];
    const float ox = off[pix * 18 + 9 + kp];
    const float mm = mo[pix * 9 + kp];
    const float py = oy + (float)(hp + kp / 3);
    const float px = ox + (float)(sow + kp % 3);
    const float y0f = floorf(py), x0f = floorf(px);
    const float y0 = fminf(fmaxf(y0f, 0.f), 65.f);
    const float y1 = fminf(fmaxf(y0f + 1.f, 0.f), 65.f);
    const float x0 = fminf(fmaxf(x0f, 0.f), 65.f);
    const float x1 = fminf(fmaxf(x0f + 1.f, 0.f), 65.f);
    const float ly = fminf(fmaxf(py, 0.f), 65.f) - y0;
    const float lx = fminf(fmaxf(px, 0.f), 65.f) - x0;
    // reference's corner<->weight pairing, matched exactly:
    float wg[4];
    wg[0] = (1.f - ly) * (1.f - lx) * mm;   // (y0,x0)
    wg[1] = (1.f - ly) * lx * mm;           // (y1,x0)
    wg[2] = ly * (1.f - lx) * mm;           // (y0,x1)
    wg[3] = ly * lx * mm;                   // (y1,x1)
    const int iy0 = (int)y0, iy1 = (int)y1, ix0 = (int)x0, ix1 = (int)x1;
    const int yy[4] = {iy0, iy1, iy0, iy1};
    const int xx[4] = {ix0, ix0, ix1, ix1};
    int og[4];
#pragma unroll
    for (int j = 0; j < 4; ++j) {
      const bool v = (yy[j] >= 1) & (yy[j] <= 64) & (xx[j] >= 1) & (xx[j] <= 64);
      int o = ((b * 64 + yy[j] - 1) * 64 + (xx[j] - 1)) * 128 + c8 * 8;
      if (!v) { o = 0; wg[j] = 0.f; }
      og[j] = o;
    }
    short8 q0 = *(const short8*)(xb + og[0]);
    short8 q1 = *(const short8*)(xb + og[1]);
    short8 q2 = *(const short8*)(xb + og[2]);
    short8 q3 = *(const short8*)(xb + og[3]);
    f32x4 Pe{0, 0, 0, 0}, Po{0, 0, 0, 0};
    auto accQ = [&](short8 s, float w) {
      union { short8 s; unsigned u[4]; } v; v.s = s;
#pragma unroll
      for (int i = 0; i < 4; ++i) {
        union { unsigned u; float f; } e, o;
        e.u = v.u[i] << 16;
        o.u = v.u[i] & 0xffff0000u;
        Pe[i] = fmaf(w, e.f, Pe[i]);
        Po[i] = fmaf(w, o.f, Po[i]);
      }
    };
    accQ(q0, wg[0]); accQ(q1, wg[1]); accQ(q2, wg[2]); accQ(q3, wg[3]);
    const int kstep = ch * 2 + (c8 >> 3);
    const size_t dst = ((size_t)(kstep * 256 + mt) << 14) + (size_t)r * 128 + swz;
    *(short8*)(feats + dst) = packEO(Pe, Po);
  }
}

// ============ k3: pure GEMM, 512 blocks x 512 threads (8 waves) ============
// Tile 128(M)x128(N), BK=64, 18 K-steps, double-buffered LDS via
// global_load_lds width-16 (feats already tile-linearized + swizzled).
// Wave (wr=wv>>2, wc=wv&3) computes 64x32; acc[4][2].
__global__ __launch_bounds__(512, 4) void dcn_gemm(
    const char* __restrict__ feats, const unsigned short* __restrict__ wtB,
    const float* __restrict__ bias, float* __restrict__ out) {
  __shared__ __align__(16) char As[2][16384];

  const int bid = blockIdx.x;
  const int b   = bid & 7;            // XCD-pinned: nt-pair of same mt share L2
  const int q   = bid >> 3;
  const int nt  = q & 1;
  const int mt  = (b << 5) | (q >> 1);
  const int t   = threadIdx.x;
  const int lane = t & 63;
  const int wv   = t >> 6;
  const int wc   = wv & 3;
  const int wr   = wv >> 2;
  const int fr   = lane & 15;
  const int kg   = lane >> 4;

  f32x4 acc[4][2];
#pragma unroll
  for (int i = 0; i < 4; ++i) { acc[i][0] = f32x4{0,0,0,0}; acc[i][1] = f32x4{0,0,0,0}; }

  const char* Abase = feats + ((size_t)mt << 14);
  const int loff = (wv << 11) + (lane << 4);

  auto stage = [&](int buf, int ks) {
    const char* g = Abase + ((size_t)ks << 22);   // kstep stride = 256*16384
    GLOAD_LDS16(g + loff,        &As[buf][wv << 11]);
    GLOAD_LDS16(g + loff + 1024, &As[buf][(wv << 11) + 1024]);
  };

  auto compute = [&](int buf, int ks) {
#pragma unroll
    for (int ks2 = 0; ks2 < 2; ++ks2) {
      short8 af[4];
#pragma unroll
      for (int m2 = 0; m2 < 4; ++m2) {
        const int rr = wr * 64 + m2 * 16 + fr;
        af[m2] = *(const short8*)&As[buf][rr * 128 + ((ks2 * 64 + kg * 16) ^ ((rr & 7) << 4))];
      }
      const int ch = ks >> 1, ksB = ((ks & 1) << 1) | ks2;
      const unsigned short* bp =
          wtB + ((((ch * 4 + ksB) * 16 + nt * 8 + wc * 2) * 64 + lane) << 3);
      short8 bf0 = *(const short8*)bp;
      short8 bf1 = *(const short8*)(bp + 512);
#pragma unroll
      for (int m2 = 0; m2 < 4; ++m2) {
        acc[m2][0] = __builtin_amdgcn_mfma_f32_16x16x32_bf16(af[m2], bf0, acc[m2][0], 0, 0, 0);
        acc[m2][1] = __builtin_amdgcn_mfma_f32_16x16x32_bf16(af[m2], bf1, acc[m2][1], 0, 0, 0);
      }
    }
  };

  stage(0, 0);
  __syncthreads();
#pragma unroll 2
  for (int ks = 0; ks < 18; ++ks) {
    const int buf = ks & 1;
    if (ks < 17) stage(buf ^ 1, ks + 1);   // issue next-tile loads first
    compute(buf, ks);
    __syncthreads();                        // vmcnt(0)+lgkmcnt(0) drain here
  }

  // epilogue: D layout col(F)=lane&15, row(M)=(lane>>4)*4+reg; fuse bias
  const int n0 = nt * 128 + wc * 32;
  const float bs0 = bias[n0 + fr];
  const float bs1 = bias[n0 + 16 + fr];
  float* obase = out + (size_t)(mt * 128 + wr * 64) * 256 + n0;
#pragma unroll
  for (int m2 = 0; m2 < 4; ++m2) {
#pragma unroll
    for (int j = 0; j < 4; ++j) {
      float* orow = obase + (size_t)(m2 * 16 + kg * 4 + j) * 256;
      orow[fr]      = acc[m2][0][j] + bs0;
      orow[16 + fr] = acc[m2][1][j] + bs1;
    }
  }
}

// ===================== fallback (ws too small): R7 kernels =================
__global__ __launch_bounds__(1024, 8) void dcn_bf16(
    const unsigned short* __restrict__ xb, const float* __restrict__ off,
    const float* __restrict__ mo, const unsigned short* __restrict__ wtB,
    const float* __restrict__ bias, float* __restrict__ out) {
  __shared__ __align__(16) char At[2][64 * 272];
  const int b  = blockIdx.x & 7;
  const int oh = blockIdx.x >> 3;
  const int t  = threadIdx.x;
  const int lane = t & 63;
  const int wv   = t >> 6;
  const int mh   = wv & 1;
  const int fq   = wv >> 1;
  const int fr   = lane & 15;
  const int kg   = lane >> 4;
  const int sow  = t >> 4;
  const int c8   = t & 15;

  f32x4 acc[2][2];
#pragma unroll
  for (int i = 0; i < 2; ++i) { acc[i][0] = f32x4{0,0,0,0}; acc[i][1] = f32x4{0,0,0,0}; }
  float oyr[2], oxr[2], mmr[2];
  int   og[4]; float wg[4];

  auto loadOff = [&](int ch, int sl) {
    const int dy = ch / 3, dxk = ch - dy * 3;
    const int r = 3 * oh + dy, hp = r & 63, kp = ((r >> 6) * 3) + dxk;
    const int pix = (b * 64 + hp) * 64 + sow;
    oyr[sl] = off[pix * 18 + kp];
    oxr[sl] = off[pix * 18 + 9 + kp];
    mmr[sl] = mo[pix * 9 + kp];
  };
  auto calcW = [&](int ch, int sl) {
    const int dy = ch / 3, dxk = ch - dy * 3;
    const int r = 3 * oh + dy, hp = r & 63, kp = ((r >> 6) * 3) + dxk;
    const float py = oyr[sl] + (float)(hp + kp / 3);
    const float px = oxr[sl] + (float)(sow + kp % 3);
    const float mm = mmr[sl];
    const float y0f = floorf(py), x0f = floorf(px);
    const float y0 = fminf(fmaxf(y0f, 0.f), 65.f);
    const float y1 = fminf(fmaxf(y0f + 1.f, 0.f), 65.f);
    const float x0 = fminf(fmaxf(x0f, 0.f), 65.f);
    const float x1 = fminf(fmaxf(x0f + 1.f, 0.f), 65.f);
    const float ly = fminf(fmaxf(py, 0.f), 65.f) - y0;
    const float lx = fminf(fmaxf(px, 0.f), 65.f) - x0;
    wg[0] = (1.f - ly) * (1.f - lx) * mm;
    wg[1] = (1.f - ly) * lx * mm;
    wg[2] = ly * (1.f - lx) * mm;
    wg[3] = ly * lx * mm;
    const int iy0 = (int)y0, iy1 = (int)y1, ix0 = (int)x0, ix1 = (int)x1;
    const int yy[4] = {iy0, iy1, iy0, iy1};
    const int xx[4] = {ix0, ix0, ix1, ix1};
#pragma unroll
    for (int j = 0; j < 4; ++j) {
      const bool v = (yy[j] >= 1) & (yy[j] <= 64) & (xx[j] >= 1) & (xx[j] <= 64);
      int o = ((b * 64 + yy[j] - 1) * 64 + (xx[j] - 1)) * 128 + c8 * 8;
      if (!v) { o = 0; wg[j] = 0.f; }
      og[j] = o;
    }
  };
  auto ldQ = [&](int c) -> short8 { return *(const short8*)(xb + og[c]); };
  auto accQ = [&](short8 s, float w, f32x4& Pe, f32x4& Po) {
    union { short8 s; unsigned u[4]; } v; v.s = s;
#pragma unroll
    for (int i = 0; i < 4; ++i) {
      union { unsigned u; float f; } e, o;
      e.u = v.u[i] << 16;
      o.u = v.u[i] & 0xffff0000u;
      Pe[i] = fmaf(w, e.f, Pe[i]);
      Po[i] = fmaf(w, o.f, Po[i]);
    }
  };
  auto mmah = [&](int buf, int ch, int ks) {
    const unsigned short* bp = wtB + (((ch * 4 + ks) * 16 + fq * 2) * 64 + lane) * 8;
    short8 bf0 = *(const short8*)bp;
    short8 bf1 = *(const short8*)(bp + 512);
    short8 af[2];
#pragma unroll
    for (int m2 = 0; m2 < 2; ++m2)
      af[m2] = *(const short8*)(At[buf] + (mh * 32 + m2 * 16 + fr) * 272 + ks * 64 + kg * 16);
#pragma unroll
    for (int m2 = 0; m2 < 2; ++m2) {
      acc[m2][0] = __builtin_amdgcn_mfma_f32_16x16x32_bf16(af[m2], bf0, acc[m2][0], 0, 0, 0);
      acc[m2][1] = __builtin_amdgcn_mfma_f32_16x16x32_bf16(af[m2], bf1, acc[m2][1], 0, 0, 0);
    }
  };
  const int wb = sow * 272 + c8 * 16;
  loadOff(0, 0); loadOff(1, 1);
  calcW(0, 0);
  {
    short8 q0 = ldQ(0), q1 = ldQ(1), q2 = ldQ(2), q3 = ldQ(3);
    f32x4 Pe{0,0,0,0}, Po{0,0,0,0};
    accQ(q0, wg[0], Pe, Po); accQ(q1, wg[1], Pe, Po);
    accQ(q2, wg[2], Pe, Po); accQ(q3, wg[3], Pe, Po);
    *(short8*)(At[0] + wb) = packEO(Pe, Po);
  }
  __syncthreads();
#pragma unroll
  for (int ch = 0; ch < 9; ++ch) {
    const int buf = ch & 1;
    const bool hv = ch < 8;
    short8 q0, q1, q2, q3;
    f32x4 Pe{0,0,0,0}, Po{0,0,0,0};
    if (hv) {
      calcW(ch + 1, (ch + 1) & 1);
      q0 = ldQ(0); q1 = ldQ(1);
    }
    mmah(buf, ch, 0);
    if (hv) {
      q2 = ldQ(2); q3 = ldQ(3);
      accQ(q0, wg[0], Pe, Po);
    }
    mmah(buf, ch, 1);
    if (hv) accQ(q1, wg[1], Pe, Po);
    if (ch < 7) loadOff(ch + 2, ch & 1);
    mmah(buf, ch, 2);
    if (hv) {
      accQ(q2, wg[2], Pe, Po);
      accQ(q3, wg[3], Pe, Po);
      *(short8*)(At[buf ^ 1] + wb) = packEO(Pe, Po);
    }
    mmah(buf, ch, 3);
    __syncthreads();
  }
  float bs[2];
#pragma unroll
  for (int nb = 0; nb < 2; ++nb) bs[nb] = bias[fq * 32 + nb * 16 + fr];
  float* orow = out + (long)(b * 64 + oh) * 64 * 256;
#pragma unroll
  for (int m2 = 0; m2 < 2; ++m2) {
#pragma unroll
    for (int j = 0; j < 4; ++j) {
      const int row = mh * 32 + m2 * 16 + kg * 4 + j;
#pragma unroll
      for (int nb = 0; nb < 2; ++nb)
        orow[row * 256 + fq * 32 + nb * 16 + fr] = acc[m2][nb][j] + bs[nb];
    }
  }
}

extern "C" void kernel_launch(void* const* d_in, const int* in_sizes, int n_in,
                              void* d_out, int out_size, void* d_ws, size_t ws_size,
                              hipStream_t stream) {
  const float* x    = (const float*)d_in[0];
  const float* off  = (const float*)d_in[1];
  const float* mo   = (const float*)d_in[2];
  const float* kf   = (const float*)d_in[3];
  const float* bias = (const float*)d_in[4];
  float* outp = (float*)d_out;
  unsigned short* wtB = (unsigned short*)d_ws;
  unsigned short* xb  = (unsigned short*)((char*)d_ws + WT_BYTES);

  prep_small<<<3200, 256, 0, stream>>>(x, kf, xb, wtB);
  if (ws_size >= WT_BYTES + XB_BYTES + FE_BYTES) {
    char* feats = (char*)d_ws + WT_BYTES + XB_BYTES;
    feats_prep<<<512, 1024, 0, stream>>>(xb, off, mo, feats);
    dcn_gemm<<<512, 512, 0, stream>>>(feats, wtB, bias, outp);
  } else {
    dcn_bf16<<<512, 1024, 0, stream>>>(xb, off, mo, wtB, bias, outp);
  }
}

// Round 10
// 51.817 us; speedup vs baseline: 1.2181x; 1.1593x over previous
//
#include <hip/hip_runtime.h>

typedef __attribute__((ext_vector_type(8))) short short8;
typedef __attribute__((ext_vector_type(4))) float f32x4;

__device__ __forceinline__ unsigned short f2bf(float f) {
  union { float f; unsigned u; } v; v.f = f;
  unsigned r = v.u + 0x7FFFu + ((v.u >> 16) & 1u);
  return (unsigned short)(r >> 16);
}

__device__ __forceinline__ short8 pack8(f32x4 a, f32x4 b) {
  short8 p;
  p[0] = (short)f2bf(a.x); p[1] = (short)f2bf(a.y);
  p[2] = (short)f2bf(a.z); p[3] = (short)f2bf(a.w);
  p[4] = (short)f2bf(b.x); p[5] = (short)f2bf(b.y);
  p[6] = (short)f2bf(b.z); p[7] = (short)f2bf(b.w);
  return p;
}

// interleave Pe (even ch) / Po (odd ch) back to channel order
__device__ __forceinline__ short8 packEO(f32x4 e, f32x4 o) {
  short8 p;
  p[0] = (short)f2bf(e.x); p[1] = (short)f2bf(o.x);
  p[2] = (short)f2bf(e.y); p[3] = (short)f2bf(o.y);
  p[4] = (short)f2bf(e.z); p[5] = (short)f2bf(o.z);
  p[6] = (short)f2bf(e.w); p[7] = (short)f2bf(o.w);
  return p;
}

// x: (8,64,64,128) f32 ; offset: (8,64,64,18) ; modulation: (8,64,64,9)
// conv_kernel: (3,3,128,256) ; bias: (256,) ; out: (8,64,64,256) f32
// GEMM view: M=32768 (b,oh,ow), K=1152, N=256.
constexpr int KKt = 1152;
constexpr int Ff  = 256;
constexpr size_t WT_BYTES = (size_t)KKt * Ff * 2;            // 589,824
constexpr size_t XB_BYTES = (size_t)8 * 64 * 64 * 128 * 2;   // 8,388,608

// ============ k1: x->bf16 (2048 blocks) | wt transpose (1152 blocks) =======
// wtB fragment-major: idx = ((((ch*4+ks)*16+ft)*4+kg)*16+fr)*8+j holds
// element (f = ft*16+fr, k = ch*128+ks*32+kg*8+j).
__global__ __launch_bounds__(256) void prep_small(
    const float* __restrict__ x, const float* __restrict__ kf,
    unsigned short* __restrict__ xb, unsigned short* __restrict__ wtB) {
  const int bid = blockIdx.x;
  if (bid < 2048) {
    int i = (bid * 256 + threadIdx.x) * 8;
    const f32x4* p = (const f32x4*)(x + i);
    *(short8*)(xb + i) = pack8(p[0], p[1]);
  } else {
    int idx = (bid - 2048) * 256 + threadIdx.x;
    int j  = idx & 7;
    int fr = (idx >> 3) & 15;
    int kg = (idx >> 7) & 3;
    int ft = (idx >> 9) & 15;
    int ks = (idx >> 13) & 3;
    int ch = idx >> 15;
    int k = ch * 128 + ks * 32 + kg * 8 + j;
    int f = ft * 16 + fr;
    wtB[idx] = f2bf(kf[k * Ff + f]);
  }
}

// ============ main: producer/consumer wave specialization ==================
// 512 blocks x 1024 threads. Waves 0..7 = consumers (pure MFMA GEMM over the
// staged A tile); waves 8..15 = producers (gather/combine/ds_write chunk k+1
// while consumers compute chunk k). One __syncthreads per chunk as the
// rendezvous; both halves execute exactly 10 barriers.
__global__ __launch_bounds__(1024, 4) void dcn_spec(
    const unsigned short* __restrict__ xb, const float* __restrict__ off,
    const float* __restrict__ mo, const unsigned short* __restrict__ wtB,
    const float* __restrict__ bias, float* __restrict__ out) {
  // A tile, row stride 272 B (+16B pad): uniform bank spread on both the
  // producers' ds_write_b128 and the consumers' af ds_read_b128.
  __shared__ __align__(16) char At[2][64 * 272];

  const int b  = blockIdx.x & 7;      // one batch image per XCD (xb L2-resident)
  const int oh = blockIdx.x >> 3;
  const int t  = threadIdx.x;

  if (t >= 512) {
    // ===================== producer half (waves 8..15) =====================
    const int pt  = t - 512;
    const int sow = pt >> 3;          // row 0..63
    const int c16 = pt & 7;           // 16-channel group
    const int wb  = sow * 272 + c16 * 32;
    float oyr[2], oxr[2], mmr[2];
    int og[4]; float wg[4];

    auto loadOff = [&](int ch, int sl) {
      const int dy = ch / 3, dxk = ch - dy * 3;
      const int r = 3 * oh + dy, hp = r & 63, kp = ((r >> 6) * 3) + dxk;
      const int pix = (b * 64 + hp) * 64 + sow;
      oyr[sl] = off[pix * 18 + kp];
      oxr[sl] = off[pix * 18 + 9 + kp];
      mmr[sl] = mo[pix * 9 + kp];
    };
    auto calcW = [&](int ch, int sl) {
      const int dy = ch / 3, dxk = ch - dy * 3;
      const int r = 3 * oh + dy, hp = r & 63, kp = ((r >> 6) * 3) + dxk;
      const float py = oyr[sl] + (float)(hp + kp / 3);
      const float px = oxr[sl] + (float)(sow + kp % 3);
      const float mm = mmr[sl];
      const float y0f = floorf(py), x0f = floorf(px);
      const float y0 = fminf(fmaxf(y0f, 0.f), 65.f);
      const float y1 = fminf(fmaxf(y0f + 1.f, 0.f), 65.f);
      const float x0 = fminf(fmaxf(x0f, 0.f), 65.f);
      const float x1 = fminf(fmaxf(x0f + 1.f, 0.f), 65.f);
      const float ly = fminf(fmaxf(py, 0.f), 65.f) - y0;
      const float lx = fminf(fmaxf(px, 0.f), 65.f) - x0;
      // reference's corner<->weight pairing, matched exactly:
      wg[0] = (1.f - ly) * (1.f - lx) * mm;   // (y0,x0)
      wg[1] = (1.f - ly) * lx * mm;           // (y1,x0)
      wg[2] = ly * (1.f - lx) * mm;           // (y0,x1)
      wg[3] = ly * lx * mm;                   // (y1,x1)
      const int iy0 = (int)y0, iy1 = (int)y1, ix0 = (int)x0, ix1 = (int)x1;
      const int yy[4] = {iy0, iy1, iy0, iy1};
      const int xx[4] = {ix0, ix0, ix1, ix1};
#pragma unroll
      for (int j = 0; j < 4; ++j) {
        const bool v = (yy[j] >= 1) & (yy[j] <= 64) & (xx[j] >= 1) & (xx[j] <= 64);
        int o = ((b * 64 + yy[j] - 1) * 64 + (xx[j] - 1)) * 128 + c16 * 16;
        if (!v) { o = 0; wg[j] = 0.f; }
        og[j] = o;
      }
    };
    auto accQ = [&](short8 s, float w, f32x4& Pe, f32x4& Po) {
      union { short8 s; unsigned u[4]; } v; v.s = s;
#pragma unroll
      for (int i = 0; i < 4; ++i) {
        union { unsigned u; float f; } e, o;
        e.u = v.u[i] << 16;
        o.u = v.u[i] & 0xffff0000u;
        Pe[i] = fmaf(w, e.f, Pe[i]);
        Po[i] = fmaf(w, o.f, Po[i]);
      }
    };
    auto pstage = [&](int ch, int sl, char* dst) {
      calcW(ch, sl);
      const short8* p0 = (const short8*)(xb + og[0]);
      const short8* p1 = (const short8*)(xb + og[1]);
      const short8* p2 = (const short8*)(xb + og[2]);
      const short8* p3 = (const short8*)(xb + og[3]);
      short8 a0 = p0[0], a1 = p0[1];
      short8 b0 = p1[0], b1 = p1[1];
      short8 c0 = p2[0], c1 = p2[1];
      short8 d0 = p3[0], d1 = p3[1];
      f32x4 Pe0{0,0,0,0}, Po0{0,0,0,0}, Pe1{0,0,0,0}, Po1{0,0,0,0};
      accQ(a0, wg[0], Pe0, Po0); accQ(a1, wg[0], Pe1, Po1);
      accQ(b0, wg[1], Pe0, Po0); accQ(b1, wg[1], Pe1, Po1);
      accQ(c0, wg[2], Pe0, Po0); accQ(c1, wg[2], Pe1, Po1);
      accQ(d0, wg[3], Pe0, Po0); accQ(d1, wg[3], Pe1, Po1);
      *(short8*)(dst + wb)      = packEO(Pe0, Po0);
      *(short8*)(dst + wb + 16) = packEO(Pe1, Po1);
    };

    loadOff(0, 0);
    loadOff(1, 1);
    pstage(0, 0, At[0]);
    __syncthreads();                         // chunk 0 ready
#pragma unroll
    for (int ch = 0; ch < 9; ++ch) {
      if (ch < 8) {
        if (ch < 7) loadOff(ch + 2, ch & 1); // prefetch next-next offsets
        pstage(ch + 1, (ch + 1) & 1, At[(ch + 1) & 1]);
      }
      __syncthreads();
    }
  } else {
    // ===================== consumer half (waves 0..7) ======================
    const int lane = t & 63;
    const int fq   = t >> 6;          // F-slice [fq*32, fq*32+32)
    const int fr   = lane & 15;
    const int kg   = lane >> 4;

    f32x4 acc[4][2];
#pragma unroll
    for (int i = 0; i < 4; ++i) { acc[i][0] = f32x4{0,0,0,0}; acc[i][1] = f32x4{0,0,0,0}; }

    auto compute = [&](int buf, int ch) {
      __builtin_amdgcn_s_setprio(1);
#pragma unroll
      for (int ks = 0; ks < 4; ++ks) {
        const unsigned short* bp = wtB + (((ch * 4 + ks) * 16 + fq * 2) * 64 + lane) * 8;
        short8 bf0 = *(const short8*)bp;
        short8 bf1 = *(const short8*)(bp + 512);
        short8 af[4];
#pragma unroll
        for (int m2 = 0; m2 < 4; ++m2)
          af[m2] = *(const short8*)(At[buf] + (m2 * 16 + fr) * 272 + ks * 64 + kg * 16);
#pragma unroll
        for (int m2 = 0; m2 < 4; ++m2) {
          acc[m2][0] = __builtin_amdgcn_mfma_f32_16x16x32_bf16(af[m2], bf0, acc[m2][0], 0, 0, 0);
          acc[m2][1] = __builtin_amdgcn_mfma_f32_16x16x32_bf16(af[m2], bf1, acc[m2][1], 0, 0, 0);
        }
      }
      __builtin_amdgcn_s_setprio(0);
    };

    __syncthreads();                         // wait for chunk 0
#pragma unroll
    for (int ch = 0; ch < 9; ++ch) {
      compute(ch & 1, ch);
      __syncthreads();
    }

    // epilogue: D layout col(F)=lane&15, row(M)=(lane>>4)*4+reg; fuse bias
    const float bs0 = bias[fq * 32 + fr];
    const float bs1 = bias[fq * 32 + 16 + fr];
    float* orow = out + (long)(b * 64 + oh) * 64 * 256;
#pragma unroll
    for (int m2 = 0; m2 < 4; ++m2) {
#pragma unroll
      for (int j = 0; j < 4; ++j) {
        const int ow = m2 * 16 + kg * 4 + j;
        orow[ow * 256 + fq * 32 + fr]      = acc[m2][0][j] + bs0;
        orow[ow * 256 + fq * 32 + 16 + fr] = acc[m2][1][j] + bs1;
      }
    }
  }
}

// ============ fallback (ws < WT+XB): R5 f32-gather kernel ==================
__global__ __launch_bounds__(512, 4) void dcn_f32(
    const float* __restrict__ x, const float* __restrict__ off,
    const float* __restrict__ mo, const unsigned short* __restrict__ wtB,
    const float* __restrict__ bias, float* __restrict__ out) {
  __shared__ __align__(16) char At[2][64 * 272];
  const int b  = blockIdx.x & 7;
  const int oh = blockIdx.x >> 3;
  const int t  = threadIdx.x;
  const int lane = t & 63;
  const int wv   = t >> 6;
  const int fr   = lane & 15;
  const int kg   = lane >> 4;
  const int sow  = t >> 3;
  const int c16  = t & 7;

  f32x4 acc[4][2];
#pragma unroll
  for (int i = 0; i < 4; ++i) { acc[i][0] = f32x4{0,0,0,0}; acc[i][1] = f32x4{0,0,0,0}; }
  float oyr[2], oxr[2], mmr[2];
  int   og[4]; float wg[4];

  auto loadOff = [&](int ch, int sl) {
    const int dy = ch / 3, dxk = ch - dy * 3;
    const int r = 3 * oh + dy, hp = r & 63, kp = ((r >> 6) * 3) + dxk;
    const int pix = (b * 64 + hp) * 64 + sow;
    oyr[sl] = off[pix * 18 + kp];
    oxr[sl] = off[pix * 18 + 9 + kp];
    mmr[sl] = mo[pix * 9 + kp];
  };
  auto calcW = [&](int ch, int sl) {
    const int dy = ch / 3, dxk = ch - dy * 3;
    const int r = 3 * oh + dy, hp = r & 63, kp = ((r >> 6) * 3) + dxk;
    const float py = oyr[sl] + (float)(hp + kp / 3);
    const float px = oxr[sl] + (float)(sow + kp % 3);
    const float mm = mmr[sl];
    const float y0f = floorf(py), x0f = floorf(px);
    const float y0 = fminf(fmaxf(y0f, 0.f), 65.f);
    const float y1 = fminf(fmaxf(y0f + 1.f, 0.f), 65.f);
    const float x0 = fminf(fmaxf(x0f, 0.f), 65.f);
    const float x1 = fminf(fmaxf(x0f + 1.f, 0.f), 65.f);
    const float ly = fminf(fmaxf(py, 0.f), 65.f) - y0;
    const float lx = fminf(fmaxf(px, 0.f), 65.f) - x0;
    wg[0] = (1.f - ly) * (1.f - lx) * mm;
    wg[1] = (1.f - ly) * lx * mm;
    wg[2] = ly * (1.f - lx) * mm;
    wg[3] = ly * lx * mm;
    const int iy0 = (int)y0, iy1 = (int)y1, ix0 = (int)x0, ix1 = (int)x1;
    const int yy[4] = {iy0, iy1, iy0, iy1};
    const int xx[4] = {ix0, ix0, ix1, ix1};
#pragma unroll
    for (int j = 0; j < 4; ++j) {
      const bool v = (yy[j] >= 1) & (yy[j] <= 64) & (xx[j] >= 1) & (xx[j] <= 64);
      int o = ((b * 64 + yy[j] - 1) * 64 + (xx[j] - 1)) * 128 + c16 * 16;
      if (!v) { o = 0; wg[j] = 0.f; }
      og[j] = o;
    }
  };
  auto ldB = [&](int ch, int ks, short8* bf) {
    const unsigned short* p = wtB + (((ch * 4 + ks) * 16 + wv * 2) * 64 + lane) * 8;
    bf[0] = *(const short8*)p;
    bf[1] = *(const short8*)(p + 512);
  };
  auto mmah = [&](int buf, int ks, const short8* bf) {
    short8 af[4];
#pragma unroll
    for (int m2 = 0; m2 < 4; ++m2)
      af[m2] = *(const short8*)(At[buf] + (m2 * 16 + fr) * 272 + ks * 64 + kg * 16);
#pragma unroll
    for (int m2 = 0; m2 < 4; ++m2)
#pragma unroll
      for (int nb = 0; nb < 2; ++nb)
        acc[m2][nb] = __builtin_amdgcn_mfma_f32_16x16x32_bf16(af[m2], bf[nb], acc[m2][nb], 0, 0, 0);
  };
  auto ldC = [&](int c, f32x4* G) {
    const f32x4* p = (const f32x4*)(x + og[c]);
    G[0] = p[0]; G[1] = p[1]; G[2] = p[2]; G[3] = p[3];
  };
  const int wb = sow * 272 + c16 * 32;
  loadOff(0, 0); loadOff(1, 1);
  calcW(0, 0);
  {
    f32x4 G0[4], G1[4];
    ldC(0, G0); ldC(1, G1);
    f32x4 P0 = wg[0]*G0[0] + wg[1]*G1[0], P1 = wg[0]*G0[1] + wg[1]*G1[1];
    f32x4 P2 = wg[0]*G0[2] + wg[1]*G1[2], P3 = wg[0]*G0[3] + wg[1]*G1[3];
    ldC(2, G0); ldC(3, G1);
    P0 += wg[2]*G0[0] + wg[3]*G1[0]; P1 += wg[2]*G0[1] + wg[3]*G1[1];
    P2 += wg[2]*G0[2] + wg[3]*G1[2]; P3 += wg[2]*G0[3] + wg[3]*G1[3];
    *(short8*)(At[0] + wb)      = pack8(P0, P1);
    *(short8*)(At[0] + wb + 16) = pack8(P2, P3);
  }
  __syncthreads();
#pragma unroll
  for (int ch = 0; ch < 9; ++ch) {
    const int buf = ch & 1;
    const bool hv = ch < 8;
    if (hv) calcW(ch + 1, (ch + 1) & 1);
    short8 bA[2], bB[2];
    f32x4 G0[4], G1[4], P0, P1, P2, P3;
    ldB(ch, 0, bA);
    if (hv) ldC(0, G0);
    ldB(ch, 1, bB);
    mmah(buf, 0, bA);
    if (hv) { P0 = wg[0]*G0[0]; P1 = wg[0]*G0[1]; P2 = wg[0]*G0[2]; P3 = wg[0]*G0[3]; }
    if (hv) ldC(1, G1);
    ldB(ch, 2, bA);
    mmah(buf, 1, bB);
    if (hv) { P0 += wg[1]*G1[0]; P1 += wg[1]*G1[1]; P2 += wg[1]*G1[2]; P3 += wg[1]*G1[3]; }
    if (hv) ldC(2, G0);
    ldB(ch, 3, bB);
    if (ch < 7) loadOff(ch + 2, ch & 1);
    mmah(buf, 2, bA);
    if (hv) { P0 += wg[2]*G0[0]; P1 += wg[2]*G0[1]; P2 += wg[2]*G0[2]; P3 += wg[2]*G0[3]; }
    if (hv) ldC(3, G1);
    mmah(buf, 3, bB);
    if (hv) {
      P0 += wg[3]*G1[0]; P1 += wg[3]*G1[1]; P2 += wg[3]*G1[2]; P3 += wg[3]*G1[3];
      *(short8*)(At[buf ^ 1] + wb)      = pack8(P0, P1);
      *(short8*)(At[buf ^ 1] + wb + 16) = pack8(P2, P3);
    }
    __syncthreads();
  }
  float bs[2];
#pragma unroll
  for (int nb = 0; nb < 2; ++nb) bs[nb] = bias[wv * 32 + nb * 16 + fr];
  float* orow = out + (long)(b * 64 + oh) * 64 * 256;
#pragma unroll
  for (int m2 = 0; m2 < 4; ++m2) {
#pragma unroll
    for (int j = 0; j < 4; ++j) {
      const int ow = m2 * 16 + kg * 4 + j;
#pragma unroll
      for (int nb = 0; nb < 2; ++nb)
        orow[ow * 256 + wv * 32 + nb * 16 + fr] = acc[m2][nb][j] + bs[nb];
    }
  }
}

__global__ void wt_prep_only(const float* __restrict__ kf, unsigned short* __restrict__ wtB) {
  int idx = blockIdx.x * 256 + threadIdx.x;
  int j  = idx & 7;
  int fr = (idx >> 3) & 15;
  int kg = (idx >> 7) & 3;
  int ft = (idx >> 9) & 15;
  int ks = (idx >> 13) & 3;
  int ch = idx >> 15;
  int k = ch * 128 + ks * 32 + kg * 8 + j;
  int f = ft * 16 + fr;
  wtB[idx] = f2bf(kf[k * Ff + f]);
}

extern "C" void kernel_launch(void* const* d_in, const int* in_sizes, int n_in,
                              void* d_out, int out_size, void* d_ws, size_t ws_size,
                              hipStream_t stream) {
  const float* x    = (const float*)d_in[0];
  const float* off  = (const float*)d_in[1];
  const float* mo   = (const float*)d_in[2];
  const float* kf   = (const float*)d_in[3];
  const float* bias = (const float*)d_in[4];
  float* outp = (float*)d_out;
  unsigned short* wtB = (unsigned short*)d_ws;

  if (ws_size >= WT_BYTES + XB_BYTES) {
    unsigned short* xb = (unsigned short*)((char*)d_ws + WT_BYTES);
    prep_small<<<3200, 256, 0, stream>>>(x, kf, xb, wtB);
    dcn_spec<<<512, 1024, 0, stream>>>(xb, off, mo, wtB, bias, outp);
  } else {
    wt_prep_only<<<1152, 256, 0, stream>>>(kf, wtB);
    dcn_f32<<<512, 512, 0, stream>>>(x, off, mo, wtB, bias, outp);
  }
}